// Round 4
// baseline (197.516 us; speedup 1.0000x reference)
//
#include <hip/hip_runtime.h>
#include <math.h>

typedef unsigned short u16;
typedef __attribute__((ext_vector_type(8))) short short8;    // 8 bf16 = 4 VGPR
typedef __attribute__((ext_vector_type(4))) short short4v;   // 4 bf16 = 2 VGPR
typedef __attribute__((ext_vector_type(4))) float floatx4;   // 16x16 MFMA C/D
typedef __attribute__((ext_vector_type(16))) float floatx16; // 32x32 MFMA C/D
typedef __attribute__((ext_vector_type(2))) float f32x2;     // v_pk_* pair

#define DIM 1024
#define SEQ 2048
#define BATCH 4
#define NTOK 8192

// workspace layout (bytes)
#define OFF_XBF   0u
#define OFF_VT    16777216u
#define OFF_WB    33554432u   // 1152 x 1024 bf16 (rows 1056+ never written: poison, discarded)
#define OFF_KANQ  35913728u   // 8192 x 16 bf16
#define OFF_KANK  36438016u
#define OFF_BKAN  36962304u   // 32 floats

__device__ __forceinline__ u16 f2bf(float x) {
  union { float f; unsigned u; } v; v.f = x;
  unsigned r = v.u + 0x7fffu + ((v.u >> 16) & 1u);   // RNE
  return (u16)(r >> 16);
}
__device__ __forceinline__ unsigned fbits(float x) {
  union { float f; unsigned u; } v; v.f = x; return v.u;
}

// ---------------------------------------------------------------------------
// k_misc: one launch for all prep (512 threads/block). (unchanged)
// ---------------------------------------------------------------------------
__global__ __launch_bounds__(512) void k_misc(
    const float* __restrict__ x, const float* __restrict__ basis,
    const float* __restrict__ Wq, const float* __restrict__ bq,
    const float* __restrict__ Wk, const float* __restrict__ bk,
    const float* __restrict__ Wv, u16* __restrict__ xbf,
    u16* __restrict__ wb, float* __restrict__ bkan) {
  __shared__ float sbT[2][128][16];   // 16 KB: transposed basis tile, dbuf
  __shared__ float red[8][16][64];    // 32 KB: cross-wave reduce
  __shared__ float r2[512];
  const int bx = blockIdx.x;
  const int tid = threadIdx.x;
  if (bx < 32) {
    const int w = bx >> 4, dblk = bx & 15;
    const int eg = tid >> 6, dl = tid & 63;
    const int d = dblk * 64 + dl;
    const float* __restrict__ Wp = (w ? Wk : Wq) + d;
    const int sf = tid >> 5, se0 = (tid & 31) * 4;
    {
      float4 bv4 = *(const float4*)(basis + sf * DIM + se0);
      sbT[0][se0 + 0][sf] = bv4.x; sbT[0][se0 + 1][sf] = bv4.y;
      sbT[0][se0 + 2][sf] = bv4.z; sbT[0][se0 + 3][sf] = bv4.w;
    }
    float acc[16];
#pragma unroll
    for (int f = 0; f < 16; ++f) acc[f] = 0.f;
    __syncthreads();
    for (int t = 0; t < 8; ++t) {
      float wv[16];
      const int eb = t * 128 + eg * 16;
#pragma unroll
      for (int u = 0; u < 16; ++u) wv[u] = Wp[(size_t)(eb + u) * DIM];
      float4 nb4;
      if (t < 7)
        nb4 = *(const float4*)(basis + sf * DIM + (t + 1) * 128 + se0);
      const int bufc = t & 1;
#pragma unroll
      for (int u = 0; u < 16; ++u) {
        const float* br = &sbT[bufc][eg * 16 + u][0];
        float4 b0 = *(const float4*)(br + 0);
        float4 b1 = *(const float4*)(br + 4);
        float4 b2 = *(const float4*)(br + 8);
        float4 b3 = *(const float4*)(br + 12);
        acc[0] = fmaf(b0.x, wv[u], acc[0]);
        acc[1] = fmaf(b0.y, wv[u], acc[1]);
        acc[2] = fmaf(b0.z, wv[u], acc[2]);
        acc[3] = fmaf(b0.w, wv[u], acc[3]);
        acc[4] = fmaf(b1.x, wv[u], acc[4]);
        acc[5] = fmaf(b1.y, wv[u], acc[5]);
        acc[6] = fmaf(b1.z, wv[u], acc[6]);
        acc[7] = fmaf(b1.w, wv[u], acc[7]);
        acc[8] = fmaf(b2.x, wv[u], acc[8]);
        acc[9] = fmaf(b2.y, wv[u], acc[9]);
        acc[10] = fmaf(b2.z, wv[u], acc[10]);
        acc[11] = fmaf(b2.w, wv[u], acc[11]);
        acc[12] = fmaf(b3.x, wv[u], acc[12]);
        acc[13] = fmaf(b3.y, wv[u], acc[13]);
        acc[14] = fmaf(b3.z, wv[u], acc[14]);
        acc[15] = fmaf(b3.w, wv[u], acc[15]);
      }
      __syncthreads();
      if (t < 7) {
        const int nb_ = (t + 1) & 1;
        sbT[nb_][se0 + 0][sf] = nb4.x; sbT[nb_][se0 + 1][sf] = nb4.y;
        sbT[nb_][se0 + 2][sf] = nb4.z; sbT[nb_][se0 + 3][sf] = nb4.w;
        __syncthreads();
      }
    }
#pragma unroll
    for (int f = 0; f < 16; ++f) red[eg][f][dl] = acc[f];
    __syncthreads();
#pragma unroll
    for (int r = 0; r < 2; ++r) {
      const int o = r * 512 + tid;        // 0..1023
      const int f = o >> 6, dd = o & 63;
      float s = 0.f;
#pragma unroll
      for (int g = 0; g < 8; ++g) s += red[g][f][dd];
      wb[(size_t)(1024 + w * 16 + f) * DIM + dblk * 64 + dd] = f2bf(s);
    }
  } else if (bx == 32) {
    const int w2 = tid >> 8, f = (tid >> 4) & 15, eg = tid & 15;
    const float* __restrict__ bb = w2 ? bk : bq;
    float a = 0.f;
    for (int e = eg * 64; e < eg * 64 + 64; ++e)
      a = fmaf(basis[f * DIM + e], bb[e], a);
    r2[tid] = a;
    __syncthreads();
    if ((tid & 15) == 0) {
      float s = 0.f;
#pragma unroll
      for (int i = 0; i < 16; ++i) s += r2[tid + i];
      bkan[tid >> 4] = s;
    }
  } else if (bx < 2081) {
    const int i = ((bx - 33) * 512 + tid) * 8;
    float4 a = *(const float4*)(x + i);
    float4 b = *(const float4*)(x + i + 4);
    short8 o;
    o[0] = f2bf(a.x); o[1] = f2bf(a.y); o[2] = f2bf(a.z); o[3] = f2bf(a.w);
    o[4] = f2bf(b.x); o[5] = f2bf(b.y); o[6] = f2bf(b.z); o[7] = f2bf(b.w);
    *(short8*)(xbf + i) = o;
  } else {
    const int i = ((bx - 2081) * 512 + tid) * 8;
    float4 a = *(const float4*)(Wv + i);
    float4 b = *(const float4*)(Wv + i + 4);
    short8 o;
    o[0] = f2bf(a.x); o[1] = f2bf(a.y); o[2] = f2bf(a.z); o[3] = f2bf(a.w);
    o[4] = f2bf(b.x); o[5] = f2bf(b.y); o[6] = f2bf(b.z); o[7] = f2bf(b.w);
    *(short8*)(wb + i) = o;
  }
}

// ---------------------------------------------------------------------------
// bf16 MFMA GEMM v7 (unchanged): 64x128 tile, XCD swizzle, XOR-swizzled LDS.
// Epilogue: V transposed + m-bit-swap(2<->3); kanq (x 1/32) / kank.
// ---------------------------------------------------------------------------
__device__ __forceinline__ void gll16(const void* g, void* s) {
  __builtin_amdgcn_global_load_lds(
      (const __attribute__((address_space(1))) void*)g,
      (__attribute__((address_space(3))) void*)s, 16, 0, 0);
}

__global__ __launch_bounds__(256) void k_gemm(
    const u16* __restrict__ A, const u16* __restrict__ B,
    const float* __restrict__ bv, const float* __restrict__ bkan,
    u16* __restrict__ vt, u16* __restrict__ kanq, u16* __restrict__ kank) {
  __shared__ u16 As[64 * 64];    //  8 KB
  __shared__ u16 Bs[128 * 64];   // 16 KB
  const int bx = blockIdx.x;
  const int xcd = bx & 7, s = bx >> 3;
  const int nb = xcd + 8 * (s / 9);    // 0..127 (64-row A tile, XCD-resident)
  const int jb = s % 9;
  const int tid = threadIdx.x;
  const int w = tid >> 6, l = tid & 63;
  const int wr = w >> 1, wc = w & 1;   // wave tile: 32 rows x 64 cols
  const int lq = l & 15, quad = l >> 4;
  const int srow = l >> 3;                          // 0..7 within 8-row chunk
  const int scol = ((l & 7) ^ (srow & 7)) * 8;      // XOR-swizzled 16B segment
  const u16* Ab = A + (size_t)(nb * 64 + w * 8 + srow) * DIM + scol;
  const u16* Bb = B + (size_t)(jb * 128 + w * 8 + srow) * DIM + scol;
  floatx4 acc[2][4];
  const floatx4 z4 = {0.f, 0.f, 0.f, 0.f};
#pragma unroll
  for (int i = 0; i < 2; ++i)
#pragma unroll
    for (int j = 0; j < 4; ++j) acc[i][j] = z4;

  for (int k0 = 0; k0 < DIM; k0 += 64) {
    __syncthreads();
#pragma unroll
    for (int i = 0; i < 2; ++i)
      gll16(Ab + (size_t)i * 32 * DIM + k0, &As[(i * 32 + w * 8) * 64]);
#pragma unroll
    for (int i = 0; i < 4; ++i)
      gll16(Bb + (size_t)i * 32 * DIM + k0, &Bs[(i * 32 + w * 8) * 64]);
    __syncthreads();
#pragma unroll
    for (int kk = 0; kk < 64; kk += 32) {
      const int sbase = (kk >> 3) + quad;           // 16B segment wanted
      const int slot = (sbase ^ (lq & 7)) * 8;      // swizzled LDS slot
      short8 af[2], bf[4];
#pragma unroll
      for (int t = 0; t < 2; ++t)
        af[t] = *(const short8*)&As[(wr * 32 + t * 16 + lq) * 64 + slot];
#pragma unroll
      for (int t = 0; t < 4; ++t)
        bf[t] = *(const short8*)&Bs[(wc * 64 + t * 16 + lq) * 64 + slot];
#pragma unroll
      for (int rt = 0; rt < 2; ++rt)
#pragma unroll
        for (int ct = 0; ct < 4; ++ct)
          acc[rt][ct] = __builtin_amdgcn_mfma_f32_16x16x32_bf16(
              af[rt], bf[ct], acc[rt][ct], 0, 0, 0);
    }
  }

  const int bt = nb >> 5;  // batch (64-row blocks never straddle: 2048/64=32)
  const size_t vtB = (size_t)bt * DIM * SEQ;
#pragma unroll
  for (int ct = 0; ct < 4; ++ct) {
    const int jbase = jb * 128 + wc * 64 + ct * 16;
    if (jbase >= 1056) continue;
    const int j = jbase + lq;
    const float bias = (jbase < 1024) ? bv[j] : bkan[j - 1024];
#pragma unroll
    for (int rt = 0; rt < 2; ++rt) {
      const int t0 = nb * 64 + wr * 32 + rt * 16 + quad * 4;
      if (jbase < 1024) {
        short4v pk;
        pk[0] = (short)f2bf(acc[rt][ct][0] + bias);
        pk[1] = (short)f2bf(acc[rt][ct][1] + bias);
        pk[2] = (short)f2bf(acc[rt][ct][2] + bias);
        pk[3] = (short)f2bf(acc[rt][ct][3] + bias);
        const int mloc = t0 & (SEQ - 1);
        const int mperm =
            (mloc & ~12) | ((mloc & 4) << 1) | ((mloc & 8) >> 1);
        *(short4v*)(vt + vtB + (size_t)j * SEQ + mperm) = pk;
      } else if (jbase < 1040) {
        const int f = j - 1024;
#pragma unroll
        for (int r = 0; r < 4; ++r)
          kanq[(size_t)(t0 + r) * 16 + f] =
              f2bf((acc[rt][ct][r] + bias) * 0.03125f);
      } else {
        const int f = j - 1040;
#pragma unroll
        for (int r = 0; r < 4; ++r)
          kank[(size_t)(t0 + r) * 16 + f] = f2bf(acc[rt][ct][r] + bias);
      }
    }
  }
}

// ---------------------------------------------------------------------------
// k_pv v6: wave remap 64q x 64d (2 qg x 2 dg) -> PV-MFMA : LDS-read = 2:1
// (halves LDS-read floor). Softmax denominator via in-register packed sums
// (+__shfl_xor(32) once at end) instead of ones-MFMA. exp poly + sums in
// packed f32 (v_pk_fma_f32). Staging / vt layout / barriers unchanged.
// Block = 128q x 128d, grid 512 (2 blocks/CU).
// ---------------------------------------------------------------------------
#define VST 88  // u16 row stride: 176 B, 16B-aligned

__global__ __launch_bounds__(256, 2) void k_pv(const u16* __restrict__ vt,
                                               const u16* __restrict__ kanq,
                                               const u16* __restrict__ kank,
                                               float* __restrict__ out) {
  __shared__ u16 Vs[2][128 * VST];
  const int bx = blockIdx.x;
  const int qb = bx >> 5;
  const int g = bx & 31;
  const int b = g >> 3, ds = g & 7;
  const int q0 = qb * 128, d0 = ds * 128;
  const int tid = threadIdx.x, w = tid >> 6, l = tid & 63;
  const int lq = l & 31, h = l >> 5;
  const int qg = w >> 1, dg = w & 1;   // wave: 64 q rows x 64 d cols
  const u16* kq = kanq + (size_t)b * SEQ * 16;
  const u16* kk = kank + (size_t)b * SEQ * 16;
  const u16* vtb = vt + ((size_t)b * DIM + d0) * SEQ;

  const short8 bq0 =
      *(const short8*)(kq + (size_t)(q0 + qg * 64 + lq) * 16 + h * 8);
  const short8 bq1 =
      *(const short8*)(kq + (size_t)(q0 + qg * 64 + 32 + lq) * 16 + h * 8);

  const int srow = tid >> 1, sc_ = tid & 1;
  const u16* sgp = vtb + (size_t)srow * SEQ + sc_ * 32;
  u16* const slA = &Vs[0][srow * VST + sc_ * 32];
  u16* const slB = &Vs[1][srow * VST + sc_ * 32];

  const floatx16 z16 = {0.f,0.f,0.f,0.f,0.f,0.f,0.f,0.f,
                        0.f,0.f,0.f,0.f,0.f,0.f,0.f,0.f};
  floatx16 accO[2][2];
#pragma unroll
  for (int qs = 0; qs < 2; ++qs)
#pragma unroll
    for (int dt = 0; dt < 2; ++dt) accO[qs][dt] = z16;
  f32x2 Lp[2];
  Lp[0][0] = 0.f; Lp[0][1] = 0.f; Lp[1][0] = 0.f; Lp[1][1] = 0.f;

  const f32x2 c16 = {0.16666667f, 0.16666667f};
  const f32x2 ch  = {0.5f, 0.5f};
  const f32x2 c1  = {1.0f, 1.0f};

  {
    short8 va = *(const short8*)(sgp);
    short8 vb_ = *(const short8*)(sgp + 8);
    short8 vc = *(const short8*)(sgp + 16);
    short8 vd = *(const short8*)(sgp + 24);
    *(short8*)(slA + 0) = va;
    *(short8*)(slA + 8) = vb_;
    *(short8*)(slA + 16) = vc;
    *(short8*)(slA + 24) = vd;
  }
  short8 kkA = *(const short8*)(kk + (size_t)(0 + lq) * 16 + h * 8);
  short8 kkB = *(const short8*)(kk + (size_t)(32 + lq) * 16 + h * 8);
  __syncthreads();

  for (int it = 0; it < SEQ / 64; ++it) {
    const int mn = (it + 1 < SEQ / 64) ? (it + 1) * 64 : 0;
    short8 nva = *(const short8*)(sgp + mn);
    short8 nvb = *(const short8*)(sgp + mn + 8);
    short8 nvc = *(const short8*)(sgp + mn + 16);
    short8 nvd = *(const short8*)(sgp + mn + 24);
    const short8 kkcA = kkA, kkcB = kkB;
    kkA = *(const short8*)(kk + (size_t)(mn + lq) * 16 + h * 8);
    kkB = *(const short8*)(kk + (size_t)(mn + 32 + lq) * 16 + h * 8);

    // QK^T + exp + pack, per 32-q sub-block (qs). Scores col=lane&31=q,
    // so the softmax denominator is lane-local (+h-partner at the end).
    short8 pf[2][4];
#pragma unroll
    for (int qs = 0; qs < 2; ++qs) {
      const short8 bq = qs ? bq1 : bq0;
      floatx16 sA =
          __builtin_amdgcn_mfma_f32_32x32x16_bf16(kkcA, bq, z16, 0, 0, 0);
      floatx16 sB =
          __builtin_amdgcn_mfma_f32_32x32x16_bf16(kkcB, bq, z16, 0, 0, 0);
      f32x2 sum; sum[0] = 0.f; sum[1] = 0.f;
      union { unsigned i[4]; short8 v; } u0, u1, u2, u3;
#pragma unroll
      for (int j = 0; j < 8; ++j) {
        f32x2 xa; xa[0] = sA[2 * j]; xa[1] = sA[2 * j + 1];
        f32x2 xb; xb[0] = sB[2 * j]; xb[1] = sB[2 * j + 1];
        f32x2 ea = __builtin_elementwise_fma(
            xa, __builtin_elementwise_fma(
                    xa, __builtin_elementwise_fma(xa, c16, ch), c1), c1);
        f32x2 eb = __builtin_elementwise_fma(
            xb, __builtin_elementwise_fma(
                    xb, __builtin_elementwise_fma(xb, c16, ch), c1), c1);
        sum += ea + eb;
        const unsigned wa =
            __builtin_amdgcn_perm(fbits(ea[1]), fbits(ea[0]), 0x07060302u);
        const unsigned wb2 =
            __builtin_amdgcn_perm(fbits(eb[1]), fbits(eb[0]), 0x07060302u);
        if (j < 4) { u0.i[j] = wa; u2.i[j] = wb2; }
        else       { u1.i[j - 4] = wa; u3.i[j - 4] = wb2; }
      }
      Lp[qs] += sum;
      pf[qs][0] = u0.v; pf[qs][1] = u1.v; pf[qs][2] = u2.v; pf[qs][3] = u3.v;
    }

    const u16* vb = &Vs[it & 1][0];
#pragma unroll
    for (int dt = 0; dt < 2; ++dt) {
      const int r = (dg * 64 + dt * 32 + lq) * VST + h * 8;
      short8 a1 = *(const short8*)(vb + r);
      short8 a2 = *(const short8*)(vb + r + 16);
      short8 a3 = *(const short8*)(vb + r + 32);
      short8 a4 = *(const short8*)(vb + r + 48);
#pragma unroll
      for (int qs = 0; qs < 2; ++qs) {
        accO[qs][dt] = __builtin_amdgcn_mfma_f32_32x32x16_bf16(
            a1, pf[qs][0], accO[qs][dt], 0, 0, 0);
        accO[qs][dt] = __builtin_amdgcn_mfma_f32_32x32x16_bf16(
            a2, pf[qs][1], accO[qs][dt], 0, 0, 0);
        accO[qs][dt] = __builtin_amdgcn_mfma_f32_32x32x16_bf16(
            a3, pf[qs][2], accO[qs][dt], 0, 0, 0);
        accO[qs][dt] = __builtin_amdgcn_mfma_f32_32x32x16_bf16(
            a4, pf[qs][3], accO[qs][dt], 0, 0, 0);
      }
    }

    u16* sl = (it & 1) ? slA : slB;
    *(short8*)(sl + 0) = nva;
    *(short8*)(sl + 8) = nvb;
    *(short8*)(sl + 16) = nvc;
    *(short8*)(sl + 24) = nvd;
    __syncthreads();
  }

  float rinv[2];
#pragma unroll
  for (int qs = 0; qs < 2; ++qs) {
    float s = Lp[qs][0] + Lp[qs][1];
    s += __shfl_xor(s, 32, 64);
    rinv[qs] = 1.f / s;
  }
#pragma unroll
  for (int qs = 0; qs < 2; ++qs) {
    float* ob =
        out + ((size_t)b * SEQ + q0 + qg * 64 + qs * 32 + lq) * DIM + d0 +
        dg * 64;
#pragma unroll
    for (int dt = 0; dt < 2; ++dt) {
#pragma unroll
      for (int gi = 0; gi < 4; ++gi) {
        float4 o;
        o.x = accO[qs][dt][gi * 4 + 0] * rinv[qs];
        o.y = accO[qs][dt][gi * 4 + 1] * rinv[qs];
        o.z = accO[qs][dt][gi * 4 + 2] * rinv[qs];
        o.w = accO[qs][dt][gi * 4 + 3] * rinv[qs];
        *(float4*)(ob + dt * 32 + gi * 8 + h * 4) = o;
      }
    }
  }
}

// ---------------------------------------------------------------------------
extern "C" void kernel_launch(void* const* d_in, const int* in_sizes, int n_in,
                              void* d_out, int out_size, void* d_ws,
                              size_t ws_size, hipStream_t stream) {
  const float* x = (const float*)d_in[0];
  const float* basis = (const float*)d_in[1];
  const float* Wq = (const float*)d_in[2];
  const float* bq = (const float*)d_in[3];
  const float* Wk = (const float*)d_in[4];
  const float* bk = (const float*)d_in[5];
  const float* Wv = (const float*)d_in[6];
  const float* bv = (const float*)d_in[7];
  float* out = (float*)d_out;
  char* w8 = (char*)d_ws;
  u16* xbf = (u16*)(w8 + OFF_XBF);
  u16* vt = (u16*)(w8 + OFF_VT);
  u16* wb = (u16*)(w8 + OFF_WB);
  u16* kanq = (u16*)(w8 + OFF_KANQ);
  u16* kank = (u16*)(w8 + OFF_KANK);
  float* bkan = (float*)(w8 + OFF_BKAN);

  k_misc<<<2337, 512, 0, stream>>>(x, basis, Wq, bq, Wk, bk, Wv, xbf, wb, bkan);
  k_gemm<<<1152, 256, 0, stream>>>(xbf, wb, bv, bkan, vt, kanq, kank);
  k_pv<<<512, 256, 0, stream>>>(vt, kanq, kank, out);
}

// Round 7
// 194.322 us; speedup vs baseline: 1.0164x; 1.0164x over previous
//
#include <hip/hip_runtime.h>
#include <math.h>

typedef unsigned short u16;
typedef __attribute__((ext_vector_type(8))) short short8;    // 8 bf16 = 4 VGPR
typedef __attribute__((ext_vector_type(4))) short short4v;   // 4 bf16 = 2 VGPR
typedef __attribute__((ext_vector_type(4))) float floatx4;   // 16x16 MFMA C/D
typedef __attribute__((ext_vector_type(16))) float floatx16; // 32x32 MFMA C/D
typedef __attribute__((ext_vector_type(2))) float f32x2;     // v_pk_* pair

#define DIM 1024
#define SEQ 2048
#define BATCH 4
#define NTOK 8192

// workspace layout (bytes)
#define OFF_XBF   0u
#define OFF_VT    16777216u
#define OFF_WB    33554432u   // 1152 x 1024 bf16 (rows 1056+ never written: poison, discarded)
#define OFF_KANQ  35913728u   // 8192 x 16 bf16
#define OFF_KANK  36438016u
#define OFF_BKAN  36962304u   // 32 floats

__device__ __forceinline__ u16 f2bf(float x) {
  union { float f; unsigned u; } v; v.f = x;
  unsigned r = v.u + 0x7fffu + ((v.u >> 16) & 1u);   // RNE
  return (u16)(r >> 16);
}
__device__ __forceinline__ unsigned fbits(float x) {
  union { float f; unsigned u; } v; v.f = x; return v.u;
}

// ---------------------------------------------------------------------------
// k_misc: one launch for all prep (512 threads/block). (unchanged)
// ---------------------------------------------------------------------------
__global__ __launch_bounds__(512) void k_misc(
    const float* __restrict__ x, const float* __restrict__ basis,
    const float* __restrict__ Wq, const float* __restrict__ bq,
    const float* __restrict__ Wk, const float* __restrict__ bk,
    const float* __restrict__ Wv, u16* __restrict__ xbf,
    u16* __restrict__ wb, float* __restrict__ bkan) {
  __shared__ float sbT[2][128][16];   // 16 KB: transposed basis tile, dbuf
  __shared__ float red[8][16][64];    // 32 KB: cross-wave reduce
  __shared__ float r2[512];
  const int bx = blockIdx.x;
  const int tid = threadIdx.x;
  if (bx < 32) {
    const int w = bx >> 4, dblk = bx & 15;
    const int eg = tid >> 6, dl = tid & 63;
    const int d = dblk * 64 + dl;
    const float* __restrict__ Wp = (w ? Wk : Wq) + d;
    const int sf = tid >> 5, se0 = (tid & 31) * 4;
    {
      float4 bv4 = *(const float4*)(basis + sf * DIM + se0);
      sbT[0][se0 + 0][sf] = bv4.x; sbT[0][se0 + 1][sf] = bv4.y;
      sbT[0][se0 + 2][sf] = bv4.z; sbT[0][se0 + 3][sf] = bv4.w;
    }
    float acc[16];
#pragma unroll
    for (int f = 0; f < 16; ++f) acc[f] = 0.f;
    __syncthreads();
    for (int t = 0; t < 8; ++t) {
      float wv[16];
      const int eb = t * 128 + eg * 16;
#pragma unroll
      for (int u = 0; u < 16; ++u) wv[u] = Wp[(size_t)(eb + u) * DIM];
      float4 nb4;
      if (t < 7)
        nb4 = *(const float4*)(basis + sf * DIM + (t + 1) * 128 + se0);
      const int bufc = t & 1;
#pragma unroll
      for (int u = 0; u < 16; ++u) {
        const float* br = &sbT[bufc][eg * 16 + u][0];
        float4 b0 = *(const float4*)(br + 0);
        float4 b1 = *(const float4*)(br + 4);
        float4 b2 = *(const float4*)(br + 8);
        float4 b3 = *(const float4*)(br + 12);
        acc[0] = fmaf(b0.x, wv[u], acc[0]);
        acc[1] = fmaf(b0.y, wv[u], acc[1]);
        acc[2] = fmaf(b0.z, wv[u], acc[2]);
        acc[3] = fmaf(b0.w, wv[u], acc[3]);
        acc[4] = fmaf(b1.x, wv[u], acc[4]);
        acc[5] = fmaf(b1.y, wv[u], acc[5]);
        acc[6] = fmaf(b1.z, wv[u], acc[6]);
        acc[7] = fmaf(b1.w, wv[u], acc[7]);
        acc[8] = fmaf(b2.x, wv[u], acc[8]);
        acc[9] = fmaf(b2.y, wv[u], acc[9]);
        acc[10] = fmaf(b2.z, wv[u], acc[10]);
        acc[11] = fmaf(b2.w, wv[u], acc[11]);
        acc[12] = fmaf(b3.x, wv[u], acc[12]);
        acc[13] = fmaf(b3.y, wv[u], acc[13]);
        acc[14] = fmaf(b3.z, wv[u], acc[14]);
        acc[15] = fmaf(b3.w, wv[u], acc[15]);
      }
      __syncthreads();
      if (t < 7) {
        const int nb_ = (t + 1) & 1;
        sbT[nb_][se0 + 0][sf] = nb4.x; sbT[nb_][se0 + 1][sf] = nb4.y;
        sbT[nb_][se0 + 2][sf] = nb4.z; sbT[nb_][se0 + 3][sf] = nb4.w;
        __syncthreads();
      }
    }
#pragma unroll
    for (int f = 0; f < 16; ++f) red[eg][f][dl] = acc[f];
    __syncthreads();
#pragma unroll
    for (int r = 0; r < 2; ++r) {
      const int o = r * 512 + tid;        // 0..1023
      const int f = o >> 6, dd = o & 63;
      float s = 0.f;
#pragma unroll
      for (int g = 0; g < 8; ++g) s += red[g][f][dd];
      wb[(size_t)(1024 + w * 16 + f) * DIM + dblk * 64 + dd] = f2bf(s);
    }
  } else if (bx == 32) {
    const int w2 = tid >> 8, f = (tid >> 4) & 15, eg = tid & 15;
    const float* __restrict__ bb = w2 ? bk : bq;
    float a = 0.f;
    for (int e = eg * 64; e < eg * 64 + 64; ++e)
      a = fmaf(basis[f * DIM + e], bb[e], a);
    r2[tid] = a;
    __syncthreads();
    if ((tid & 15) == 0) {
      float s = 0.f;
#pragma unroll
      for (int i = 0; i < 16; ++i) s += r2[tid + i];
      bkan[tid >> 4] = s;
    }
  } else if (bx < 2081) {
    const int i = ((bx - 33) * 512 + tid) * 8;
    float4 a = *(const float4*)(x + i);
    float4 b = *(const float4*)(x + i + 4);
    short8 o;
    o[0] = f2bf(a.x); o[1] = f2bf(a.y); o[2] = f2bf(a.z); o[3] = f2bf(a.w);
    o[4] = f2bf(b.x); o[5] = f2bf(b.y); o[6] = f2bf(b.z); o[7] = f2bf(b.w);
    *(short8*)(xbf + i) = o;
  } else {
    const int i = ((bx - 2081) * 512 + tid) * 8;
    float4 a = *(const float4*)(Wv + i);
    float4 b = *(const float4*)(Wv + i + 4);
    short8 o;
    o[0] = f2bf(a.x); o[1] = f2bf(a.y); o[2] = f2bf(a.z); o[3] = f2bf(a.w);
    o[4] = f2bf(b.x); o[5] = f2bf(b.y); o[6] = f2bf(b.z); o[7] = f2bf(b.w);
    *(short8*)(wb + i) = o;
  }
}

// ---------------------------------------------------------------------------
// bf16 MFMA GEMM v7 (unchanged): 64x128 tile, XCD swizzle, XOR-swizzled LDS.
// Epilogue: V transposed + m-bit-swap(2<->3); kanq (x 1/32) / kank.
// ---------------------------------------------------------------------------
__device__ __forceinline__ void gll16(const void* g, void* s) {
  __builtin_amdgcn_global_load_lds(
      (const __attribute__((address_space(1))) void*)g,
      (__attribute__((address_space(3))) void*)s, 16, 0, 0);
}

__global__ __launch_bounds__(256) void k_gemm(
    const u16* __restrict__ A, const u16* __restrict__ B,
    const float* __restrict__ bv, const float* __restrict__ bkan,
    u16* __restrict__ vt, u16* __restrict__ kanq, u16* __restrict__ kank) {
  __shared__ u16 As[64 * 64];    //  8 KB
  __shared__ u16 Bs[128 * 64];   // 16 KB
  const int bx = blockIdx.x;
  const int xcd = bx & 7, s = bx >> 3;
  const int nb = xcd + 8 * (s / 9);    // 0..127 (64-row A tile, XCD-resident)
  const int jb = s % 9;
  const int tid = threadIdx.x;
  const int w = tid >> 6, l = tid & 63;
  const int wr = w >> 1, wc = w & 1;   // wave tile: 32 rows x 64 cols
  const int lq = l & 15, quad = l >> 4;
  const int srow = l >> 3;                          // 0..7 within 8-row chunk
  const int scol = ((l & 7) ^ (srow & 7)) * 8;      // XOR-swizzled 16B segment
  const u16* Ab = A + (size_t)(nb * 64 + w * 8 + srow) * DIM + scol;
  const u16* Bb = B + (size_t)(jb * 128 + w * 8 + srow) * DIM + scol;
  floatx4 acc[2][4];
  const floatx4 z4 = {0.f, 0.f, 0.f, 0.f};
#pragma unroll
  for (int i = 0; i < 2; ++i)
#pragma unroll
    for (int j = 0; j < 4; ++j) acc[i][j] = z4;

  for (int k0 = 0; k0 < DIM; k0 += 64) {
    __syncthreads();
#pragma unroll
    for (int i = 0; i < 2; ++i)
      gll16(Ab + (size_t)i * 32 * DIM + k0, &As[(i * 32 + w * 8) * 64]);
#pragma unroll
    for (int i = 0; i < 4; ++i)
      gll16(Bb + (size_t)i * 32 * DIM + k0, &Bs[(i * 32 + w * 8) * 64]);
    __syncthreads();
#pragma unroll
    for (int kk = 0; kk < 64; kk += 32) {
      const int sbase = (kk >> 3) + quad;           // 16B segment wanted
      const int slot = (sbase ^ (lq & 7)) * 8;      // swizzled LDS slot
      short8 af[2], bf[4];
#pragma unroll
      for (int t = 0; t < 2; ++t)
        af[t] = *(const short8*)&As[(wr * 32 + t * 16 + lq) * 64 + slot];
#pragma unroll
      for (int t = 0; t < 4; ++t)
        bf[t] = *(const short8*)&Bs[(wc * 64 + t * 16 + lq) * 64 + slot];
#pragma unroll
      for (int rt = 0; rt < 2; ++rt)
#pragma unroll
        for (int ct = 0; ct < 4; ++ct)
          acc[rt][ct] = __builtin_amdgcn_mfma_f32_16x16x32_bf16(
              af[rt], bf[ct], acc[rt][ct], 0, 0, 0);
    }
  }

  const int bt = nb >> 5;  // batch (64-row blocks never straddle: 2048/64=32)
  const size_t vtB = (size_t)bt * DIM * SEQ;
#pragma unroll
  for (int ct = 0; ct < 4; ++ct) {
    const int jbase = jb * 128 + wc * 64 + ct * 16;
    if (jbase >= 1056) continue;
    const int j = jbase + lq;
    const float bias = (jbase < 1024) ? bv[j] : bkan[j - 1024];
#pragma unroll
    for (int rt = 0; rt < 2; ++rt) {
      const int t0 = nb * 64 + wr * 32 + rt * 16 + quad * 4;
      if (jbase < 1024) {
        short4v pk;
        pk[0] = (short)f2bf(acc[rt][ct][0] + bias);
        pk[1] = (short)f2bf(acc[rt][ct][1] + bias);
        pk[2] = (short)f2bf(acc[rt][ct][2] + bias);
        pk[3] = (short)f2bf(acc[rt][ct][3] + bias);
        const int mloc = t0 & (SEQ - 1);
        const int mperm =
            (mloc & ~12) | ((mloc & 4) << 1) | ((mloc & 8) >> 1);
        *(short4v*)(vt + vtB + (size_t)j * SEQ + mperm) = pk;
      } else if (jbase < 1040) {
        const int f = j - 1024;
#pragma unroll
        for (int r = 0; r < 4; ++r)
          kanq[(size_t)(t0 + r) * 16 + f] =
              f2bf((acc[rt][ct][r] + bias) * 0.03125f);
      } else {
        const int f = j - 1040;
#pragma unroll
        for (int r = 0; r < 4; ++r)
          kank[(size_t)(t0 + r) * 16 + f] = f2bf(acc[rt][ct][r] + bias);
      }
    }
  }
}

// ---------------------------------------------------------------------------
// k_pv v7: back to v5's 32q x 128d wave map (no exp duplication), plus:
//  (a) P double-pipeline (T15): iter t runs QK(t)+exp(t) on the VALU while
//      the MFMA pipe consumes pf(t-1) x V(t-1) -- same basic block (iter 0
//      peeled, no branch) so the scheduler can interleave the two pipes.
//      2 barriers/iter: PV reads Vs[(t-1)&1] before barrier-1, staging
//      writes V(t+1) into that same buffer after it.
//  (b) in-register softmax denominator (lane-local packed sums +
//      __shfl_xor(32) once) -- removes the 4 ones-MFMA per wave-iter.
//      (verified correct in the v6 run: same layout, absmax unchanged.)
// Block = 128q x 128d, grid 512 (2 blocks/CU).
// ---------------------------------------------------------------------------
#define VST 88  // u16 row stride: 176 B, 16B-aligned

__global__ __launch_bounds__(256, 2) void k_pv(const u16* __restrict__ vt,
                                               const u16* __restrict__ kanq,
                                               const u16* __restrict__ kank,
                                               float* __restrict__ out) {
  __shared__ u16 Vs[2][128 * VST];
  const int bx = blockIdx.x;
  const int qb = bx >> 5;
  const int g = bx & 31;
  const int b = g >> 3, ds = g & 7;
  const int q0 = qb * 128, d0 = ds * 128;
  const int tid = threadIdx.x, w = tid >> 6, l = tid & 63;
  const int lq = l & 31, h = l >> 5;
  const u16* kq = kanq + (size_t)b * SEQ * 16;
  const u16* kk = kank + (size_t)b * SEQ * 16;
  const u16* vtb = vt + ((size_t)b * DIM + d0) * SEQ;

  const short8 bqf =
      *(const short8*)(kq + (size_t)(q0 + w * 32 + lq) * 16 + h * 8);

  const int srow = tid >> 1, sc_ = tid & 1;
  const u16* sgp = vtb + (size_t)srow * SEQ + sc_ * 32;
  u16* const sl0 = &Vs[0][srow * VST + sc_ * 32];
  u16* const sl1 = &Vs[1][srow * VST + sc_ * 32];

  const floatx16 z16 = {0.f,0.f,0.f,0.f,0.f,0.f,0.f,0.f,
                        0.f,0.f,0.f,0.f,0.f,0.f,0.f,0.f};
  floatx16 accO[4];
#pragma unroll
  for (int dt = 0; dt < 4; ++dt) accO[dt] = z16;
  f32x2 Lp; Lp[0] = 0.f; Lp[1] = 0.f;

  const f32x2 c16 = {0.16666667f, 0.16666667f};
  const f32x2 ch  = {0.5f, 0.5f};
  const f32x2 c1  = {1.0f, 1.0f};

  // exp + pack one 32m x 32q score pair -> 4 bf16 P fragments, accum Lp
  auto exppack = [&](const floatx16& sA, const floatx16& sB,
                     short8& o1A, short8& o2A, short8& o1B, short8& o2B) {
    union { floatx16 v; f32x2 p[8]; } ua, ub;
    ua.v = sA; ub.v = sB;
    f32x2 sum; sum[0] = 0.f; sum[1] = 0.f;
    union { unsigned i[4]; short8 v; } u1a, u2a, u1b, u2b;
#pragma unroll
    for (int j = 0; j < 8; ++j) {
      f32x2 xa = ua.p[j], xb = ub.p[j];
      f32x2 ea = __builtin_elementwise_fma(
          xa, __builtin_elementwise_fma(
                  xa, __builtin_elementwise_fma(xa, c16, ch), c1), c1);
      f32x2 eb = __builtin_elementwise_fma(
          xb, __builtin_elementwise_fma(
                  xb, __builtin_elementwise_fma(xb, c16, ch), c1), c1);
      sum += ea; sum += eb;
      const unsigned wa =
          __builtin_amdgcn_perm(fbits(ea[1]), fbits(ea[0]), 0x07060302u);
      const unsigned wb2 =
          __builtin_amdgcn_perm(fbits(eb[1]), fbits(eb[0]), 0x07060302u);
      if (j < 4) { u1a.i[j] = wa; u1b.i[j] = wb2; }
      else       { u2a.i[j - 4] = wa; u2b.i[j - 4] = wb2; }
    }
    Lp += sum;
    o1A = u1a.v; o2A = u2a.v; o1B = u1b.v; o2B = u2b.v;
  };

  // PV for one staged 64m chunk (16 MFMA, 16 ds_read_b128)
  auto pv = [&](const u16* vb, const short8& p1A, const short8& p2A,
                const short8& p1B, const short8& p2B) {
#pragma unroll
    for (int dt = 0; dt < 4; ++dt) {
      const int r = (dt * 32 + lq) * VST + h * 8;
      short8 a1 = *(const short8*)(vb + r);
      short8 a2 = *(const short8*)(vb + r + 16);
      short8 a3 = *(const short8*)(vb + r + 32);
      short8 a4 = *(const short8*)(vb + r + 48);
      accO[dt] = __builtin_amdgcn_mfma_f32_32x32x16_bf16(a1, p1A, accO[dt], 0, 0, 0);
      accO[dt] = __builtin_amdgcn_mfma_f32_32x32x16_bf16(a2, p2A, accO[dt], 0, 0, 0);
      accO[dt] = __builtin_amdgcn_mfma_f32_32x32x16_bf16(a3, p1B, accO[dt], 0, 0, 0);
      accO[dt] = __builtin_amdgcn_mfma_f32_32x32x16_bf16(a4, p2B, accO[dt], 0, 0, 0);
    }
  };

  // prologue: stage V(0) into Vs[0]; load kk(0)
  {
    short8 va = *(const short8*)(sgp);
    short8 vb_ = *(const short8*)(sgp + 8);
    short8 vc = *(const short8*)(sgp + 16);
    short8 vd = *(const short8*)(sgp + 24);
    *(short8*)(sl0 + 0) = va;
    *(short8*)(sl0 + 8) = vb_;
    *(short8*)(sl0 + 16) = vc;
    *(short8*)(sl0 + 24) = vd;
  }
  short8 kkA = *(const short8*)(kk + (size_t)(0 + lq) * 16 + h * 8);
  short8 kkB = *(const short8*)(kk + (size_t)(32 + lq) * 16 + h * 8);
  __syncthreads();

  short8 pf1A, pf2A, pf1B, pf2B;

  // it = 0 peeled: QK(0)+exp(0) only (no PV yet); stage V(1) -> Vs[1]
  {
    short8 nva = *(const short8*)(sgp + 64);
    short8 nvb = *(const short8*)(sgp + 64 + 8);
    short8 nvc = *(const short8*)(sgp + 64 + 16);
    short8 nvd = *(const short8*)(sgp + 64 + 24);
    const short8 kkcA = kkA, kkcB = kkB;
    kkA = *(const short8*)(kk + (size_t)(64 + lq) * 16 + h * 8);
    kkB = *(const short8*)(kk + (size_t)(64 + 32 + lq) * 16 + h * 8);
    floatx16 scA =
        __builtin_amdgcn_mfma_f32_32x32x16_bf16(kkcA, bqf, z16, 0, 0, 0);
    floatx16 scB =
        __builtin_amdgcn_mfma_f32_32x32x16_bf16(kkcB, bqf, z16, 0, 0, 0);
    exppack(scA, scB, pf1A, pf2A, pf1B, pf2B);
    __syncthreads();
    *(short8*)(sl1 + 0) = nva;
    *(short8*)(sl1 + 8) = nvb;
    *(short8*)(sl1 + 16) = nvc;
    *(short8*)(sl1 + 24) = nvd;
    __syncthreads();
  }

  for (int it = 1; it < SEQ / 64; ++it) {
    const int mn = (it + 1 < SEQ / 64) ? (it + 1) * 64 : 0;
    short8 nva = *(const short8*)(sgp + mn);
    short8 nvb = *(const short8*)(sgp + mn + 8);
    short8 nvc = *(const short8*)(sgp + mn + 16);
    short8 nvd = *(const short8*)(sgp + mn + 24);
    const short8 kkcA = kkA, kkcB = kkB;
    kkA = *(const short8*)(kk + (size_t)(mn + lq) * 16 + h * 8);
    kkB = *(const short8*)(kk + (size_t)(mn + 32 + lq) * 16 + h * 8);

    // QK(it)
    floatx16 scA =
        __builtin_amdgcn_mfma_f32_32x32x16_bf16(kkcA, bqf, z16, 0, 0, 0);
    floatx16 scB =
        __builtin_amdgcn_mfma_f32_32x32x16_bf16(kkcB, bqf, z16, 0, 0, 0);

    // PV(it-1) from Vs[(it-1)&1] -- MFMA pipe; exp(it) below -- VALU pipe.
    // Same basic block: scheduler interleaves them.
    pv(&Vs[(it & 1) ^ 1][0], pf1A, pf2A, pf1B, pf2B);
    exppack(scA, scB, pf1A, pf2A, pf1B, pf2B);

    __syncthreads();   // barrier 1: PV reads of Vs[(it-1)&1] complete
    u16* sl = ((it & 1) ^ 1) ? sl1 : sl0;   // write V(it+1) -> Vs[(it+1)&1]
    *(short8*)(sl + 0) = nva;
    *(short8*)(sl + 8) = nvb;
    *(short8*)(sl + 16) = nvc;
    *(short8*)(sl + 24) = nvd;
    __syncthreads();   // barrier 2: staging visible
  }

  // epilogue: PV(31) from Vs[1]
  pv(&Vs[1][0], pf1A, pf2A, pf1B, pf2B);

  float sden = Lp[0] + Lp[1];
  sden += __shfl_xor(sden, 32, 64);
  const float rinv = 1.f / sden;
  float* ob = out + ((size_t)b * SEQ + q0 + w * 32 + lq) * DIM + d0;
#pragma unroll
  for (int dt = 0; dt < 4; ++dt) {
#pragma unroll
    for (int gi = 0; gi < 4; ++gi) {
      float4 o;
      o.x = accO[dt][gi * 4 + 0] * rinv;
      o.y = accO[dt][gi * 4 + 1] * rinv;
      o.z = accO[dt][gi * 4 + 2] * rinv;
      o.w = accO[dt][gi * 4 + 3] * rinv;
      *(float4*)(ob + dt * 32 + gi * 8 + h * 4) = o;
    }
  }
}

// ---------------------------------------------------------------------------
extern "C" void kernel_launch(void* const* d_in, const int* in_sizes, int n_in,
                              void* d_out, int out_size, void* d_ws,
                              size_t ws_size, hipStream_t stream) {
  const float* x = (const float*)d_in[0];
  const float* basis = (const float*)d_in[1];
  const float* Wq = (const float*)d_in[2];
  const float* bq = (const float*)d_in[3];
  const float* Wk = (const float*)d_in[4];
  const float* bk = (const float*)d_in[5];
  const float* Wv = (const float*)d_in[6];
  const float* bv = (const float*)d_in[7];
  float* out = (float*)d_out;
  char* w8 = (char*)d_ws;
  u16* xbf = (u16*)(w8 + OFF_XBF);
  u16* vt = (u16*)(w8 + OFF_VT);
  u16* wb = (u16*)(w8 + OFF_WB);
  u16* kanq = (u16*)(w8 + OFF_KANQ);
  u16* kank = (u16*)(w8 + OFF_KANK);
  float* bkan = (float*)(w8 + OFF_BKAN);

  k_misc<<<2337, 512, 0, stream>>>(x, basis, Wq, bq, Wk, bk, Wv, xbf, wb, bkan);
  k_gemm<<<1152, 256, 0, stream>>>(xbf, wb, bv, bkan, vt, kanq, kank);
  k_pv<<<512, 256, 0, stream>>>(vt, kanq, kank, out);
}

// Round 10
// 192.230 us; speedup vs baseline: 1.0275x; 1.0109x over previous
//
#include <hip/hip_runtime.h>
#include <math.h>

typedef unsigned short u16;
typedef __attribute__((ext_vector_type(8))) short short8;    // 8 bf16 = 4 VGPR
typedef __attribute__((ext_vector_type(4))) short short4v;   // 4 bf16 = 2 VGPR
typedef __attribute__((ext_vector_type(4))) float floatx4;   // 16x16 MFMA C/D
typedef __attribute__((ext_vector_type(16))) float floatx16; // 32x32 MFMA C/D
typedef __attribute__((ext_vector_type(2))) float f32x2;     // v_pk_* pair

#define DIM 1024
#define SEQ 2048
#define BATCH 4
#define NTOK 8192

// workspace layout (bytes)
#define OFF_XBF   0u
#define OFF_VT    16777216u
#define OFF_WB    33554432u   // 1152 x 1024 bf16 (rows 1056+ never written: poison, discarded)
#define OFF_KANQ  35913728u   // 8192 x 16 bf16
#define OFF_KANK  36438016u
#define OFF_BKAN  36962304u   // 32 floats

__device__ __forceinline__ u16 f2bf(float x) {
  union { float f; unsigned u; } v; v.f = x;
  unsigned r = v.u + 0x7fffu + ((v.u >> 16) & 1u);   // RNE
  return (u16)(r >> 16);
}
__device__ __forceinline__ unsigned fbits(float x) {
  union { float f; unsigned u; } v; v.f = x; return v.u;
}

// ---------------------------------------------------------------------------
// k_misc: one launch for all prep (512 threads/block). (unchanged)
// ---------------------------------------------------------------------------
__global__ __launch_bounds__(512) void k_misc(
    const float* __restrict__ x, const float* __restrict__ basis,
    const float* __restrict__ Wq, const float* __restrict__ bq,
    const float* __restrict__ Wk, const float* __restrict__ bk,
    const float* __restrict__ Wv, u16* __restrict__ xbf,
    u16* __restrict__ wb, float* __restrict__ bkan) {
  __shared__ float sbT[2][128][16];   // 16 KB: transposed basis tile, dbuf
  __shared__ float red[8][16][64];    // 32 KB: cross-wave reduce
  __shared__ float r2[512];
  const int bx = blockIdx.x;
  const int tid = threadIdx.x;
  if (bx < 32) {
    const int w = bx >> 4, dblk = bx & 15;
    const int eg = tid >> 6, dl = tid & 63;
    const int d = dblk * 64 + dl;
    const float* __restrict__ Wp = (w ? Wk : Wq) + d;
    const int sf = tid >> 5, se0 = (tid & 31) * 4;
    {
      float4 bv4 = *(const float4*)(basis + sf * DIM + se0);
      sbT[0][se0 + 0][sf] = bv4.x; sbT[0][se0 + 1][sf] = bv4.y;
      sbT[0][se0 + 2][sf] = bv4.z; sbT[0][se0 + 3][sf] = bv4.w;
    }
    float acc[16];
#pragma unroll
    for (int f = 0; f < 16; ++f) acc[f] = 0.f;
    __syncthreads();
    for (int t = 0; t < 8; ++t) {
      float wv[16];
      const int eb = t * 128 + eg * 16;
#pragma unroll
      for (int u = 0; u < 16; ++u) wv[u] = Wp[(size_t)(eb + u) * DIM];
      float4 nb4;
      if (t < 7)
        nb4 = *(const float4*)(basis + sf * DIM + (t + 1) * 128 + se0);
      const int bufc = t & 1;
#pragma unroll
      for (int u = 0; u < 16; ++u) {
        const float* br = &sbT[bufc][eg * 16 + u][0];
        float4 b0 = *(const float4*)(br + 0);
        float4 b1 = *(const float4*)(br + 4);
        float4 b2 = *(const float4*)(br + 8);
        float4 b3 = *(const float4*)(br + 12);
        acc[0] = fmaf(b0.x, wv[u], acc[0]);
        acc[1] = fmaf(b0.y, wv[u], acc[1]);
        acc[2] = fmaf(b0.z, wv[u], acc[2]);
        acc[3] = fmaf(b0.w, wv[u], acc[3]);
        acc[4] = fmaf(b1.x, wv[u], acc[4]);
        acc[5] = fmaf(b1.y, wv[u], acc[5]);
        acc[6] = fmaf(b1.z, wv[u], acc[6]);
        acc[7] = fmaf(b1.w, wv[u], acc[7]);
        acc[8] = fmaf(b2.x, wv[u], acc[8]);
        acc[9] = fmaf(b2.y, wv[u], acc[9]);
        acc[10] = fmaf(b2.z, wv[u], acc[10]);
        acc[11] = fmaf(b2.w, wv[u], acc[11]);
        acc[12] = fmaf(b3.x, wv[u], acc[12]);
        acc[13] = fmaf(b3.y, wv[u], acc[13]);
        acc[14] = fmaf(b3.z, wv[u], acc[14]);
        acc[15] = fmaf(b3.w, wv[u], acc[15]);
      }
      __syncthreads();
      if (t < 7) {
        const int nb_ = (t + 1) & 1;
        sbT[nb_][se0 + 0][sf] = nb4.x; sbT[nb_][se0 + 1][sf] = nb4.y;
        sbT[nb_][se0 + 2][sf] = nb4.z; sbT[nb_][se0 + 3][sf] = nb4.w;
        __syncthreads();
      }
    }
#pragma unroll
    for (int f = 0; f < 16; ++f) red[eg][f][dl] = acc[f];
    __syncthreads();
#pragma unroll
    for (int r = 0; r < 2; ++r) {
      const int o = r * 512 + tid;        // 0..1023
      const int f = o >> 6, dd = o & 63;
      float s = 0.f;
#pragma unroll
      for (int g = 0; g < 8; ++g) s += red[g][f][dd];
      wb[(size_t)(1024 + w * 16 + f) * DIM + dblk * 64 + dd] = f2bf(s);
    }
  } else if (bx == 32) {
    const int w2 = tid >> 8, f = (tid >> 4) & 15, eg = tid & 15;
    const float* __restrict__ bb = w2 ? bk : bq;
    float a = 0.f;
    for (int e = eg * 64; e < eg * 64 + 64; ++e)
      a = fmaf(basis[f * DIM + e], bb[e], a);
    r2[tid] = a;
    __syncthreads();
    if ((tid & 15) == 0) {
      float s = 0.f;
#pragma unroll
      for (int i = 0; i < 16; ++i) s += r2[tid + i];
      bkan[tid >> 4] = s;
    }
  } else if (bx < 2081) {
    const int i = ((bx - 33) * 512 + tid) * 8;
    float4 a = *(const float4*)(x + i);
    float4 b = *(const float4*)(x + i + 4);
    short8 o;
    o[0] = f2bf(a.x); o[1] = f2bf(a.y); o[2] = f2bf(a.z); o[3] = f2bf(a.w);
    o[4] = f2bf(b.x); o[5] = f2bf(b.y); o[6] = f2bf(b.z); o[7] = f2bf(b.w);
    *(short8*)(xbf + i) = o;
  } else {
    const int i = ((bx - 2081) * 512 + tid) * 8;
    float4 a = *(const float4*)(Wv + i);
    float4 b = *(const float4*)(Wv + i + 4);
    short8 o;
    o[0] = f2bf(a.x); o[1] = f2bf(a.y); o[2] = f2bf(a.z); o[3] = f2bf(a.w);
    o[4] = f2bf(b.x); o[5] = f2bf(b.y); o[6] = f2bf(b.z); o[7] = f2bf(b.w);
    *(short8*)(wb + i) = o;
  }
}

// ---------------------------------------------------------------------------
// bf16 MFMA GEMM v7 (unchanged): 64x128 tile, XCD swizzle, XOR-swizzled LDS.
// Epilogue: V transposed + m-bit-swap(2<->3); kanq (x 1/32) / kank.
// ---------------------------------------------------------------------------
__device__ __forceinline__ void gll16(const void* g, void* s) {
  __builtin_amdgcn_global_load_lds(
      (const __attribute__((address_space(1))) void*)g,
      (__attribute__((address_space(3))) void*)s, 16, 0, 0);
}

__global__ __launch_bounds__(256) void k_gemm(
    const u16* __restrict__ A, const u16* __restrict__ B,
    const float* __restrict__ bv, const float* __restrict__ bkan,
    u16* __restrict__ vt, u16* __restrict__ kanq, u16* __restrict__ kank) {
  __shared__ u16 As[64 * 64];    //  8 KB
  __shared__ u16 Bs[128 * 64];   // 16 KB
  const int bx = blockIdx.x;
  const int xcd = bx & 7, s = bx >> 3;
  const int nb = xcd + 8 * (s / 9);    // 0..127 (64-row A tile, XCD-resident)
  const int jb = s % 9;
  const int tid = threadIdx.x;
  const int w = tid >> 6, l = tid & 63;
  const int wr = w >> 1, wc = w & 1;   // wave tile: 32 rows x 64 cols
  const int lq = l & 15, quad = l >> 4;
  const int srow = l >> 3;                          // 0..7 within 8-row chunk
  const int scol = ((l & 7) ^ (srow & 7)) * 8;      // XOR-swizzled 16B segment
  const u16* Ab = A + (size_t)(nb * 64 + w * 8 + srow) * DIM + scol;
  const u16* Bb = B + (size_t)(jb * 128 + w * 8 + srow) * DIM + scol;
  floatx4 acc[2][4];
  const floatx4 z4 = {0.f, 0.f, 0.f, 0.f};
#pragma unroll
  for (int i = 0; i < 2; ++i)
#pragma unroll
    for (int j = 0; j < 4; ++j) acc[i][j] = z4;

  for (int k0 = 0; k0 < DIM; k0 += 64) {
    __syncthreads();
#pragma unroll
    for (int i = 0; i < 2; ++i)
      gll16(Ab + (size_t)i * 32 * DIM + k0, &As[(i * 32 + w * 8) * 64]);
#pragma unroll
    for (int i = 0; i < 4; ++i)
      gll16(Bb + (size_t)i * 32 * DIM + k0, &Bs[(i * 32 + w * 8) * 64]);
    __syncthreads();
#pragma unroll
    for (int kk = 0; kk < 64; kk += 32) {
      const int sbase = (kk >> 3) + quad;           // 16B segment wanted
      const int slot = (sbase ^ (lq & 7)) * 8;      // swizzled LDS slot
      short8 af[2], bf[4];
#pragma unroll
      for (int t = 0; t < 2; ++t)
        af[t] = *(const short8*)&As[(wr * 32 + t * 16 + lq) * 64 + slot];
#pragma unroll
      for (int t = 0; t < 4; ++t)
        bf[t] = *(const short8*)&Bs[(wc * 64 + t * 16 + lq) * 64 + slot];
#pragma unroll
      for (int rt = 0; rt < 2; ++rt)
#pragma unroll
        for (int ct = 0; ct < 4; ++ct)
          acc[rt][ct] = __builtin_amdgcn_mfma_f32_16x16x32_bf16(
              af[rt], bf[ct], acc[rt][ct], 0, 0, 0);
    }
  }

  const int bt = nb >> 5;  // batch (64-row blocks never straddle: 2048/64=32)
  const size_t vtB = (size_t)bt * DIM * SEQ;
#pragma unroll
  for (int ct = 0; ct < 4; ++ct) {
    const int jbase = jb * 128 + wc * 64 + ct * 16;
    if (jbase >= 1056) continue;
    const int j = jbase + lq;
    const float bias = (jbase < 1024) ? bv[j] : bkan[j - 1024];
#pragma unroll
    for (int rt = 0; rt < 2; ++rt) {
      const int t0 = nb * 64 + wr * 32 + rt * 16 + quad * 4;
      if (jbase < 1024) {
        short4v pk;
        pk[0] = (short)f2bf(acc[rt][ct][0] + bias);
        pk[1] = (short)f2bf(acc[rt][ct][1] + bias);
        pk[2] = (short)f2bf(acc[rt][ct][2] + bias);
        pk[3] = (short)f2bf(acc[rt][ct][3] + bias);
        const int mloc = t0 & (SEQ - 1);
        const int mperm =
            (mloc & ~12) | ((mloc & 4) << 1) | ((mloc & 8) >> 1);
        *(short4v*)(vt + vtB + (size_t)j * SEQ + mperm) = pk;
      } else if (jbase < 1040) {
        const int f = j - 1024;
#pragma unroll
        for (int r = 0; r < 4; ++r)
          kanq[(size_t)(t0 + r) * 16 + f] =
              f2bf((acc[rt][ct][r] + bias) * 0.03125f);
      } else {
        const int f = j - 1040;
#pragma unroll
        for (int r = 0; r < 4; ++r)
          kank[(size_t)(t0 + r) * 16 + f] = f2bf(acc[rt][ct][r] + bias);
      }
    }
  }
}

// ---------------------------------------------------------------------------
// k_pv v8: k_gemm-style staging. global_load_lds with pre-swizzled per-lane
// global source (seg ^= row&7 involution), linear 64-u16 LDS rows, XOR on
// read. 3 buffers, ONE barrier/iter: iter t stages chunk t+1 -> buf[(t+1)%3],
// reads chunk t-1 (P-delay from v7) from buf[(t-1)%3]. exp j-chunks manually
// interleaved into the PV dt-loop. In-register softmax denominator kept.
// Block = 128q x 128d, grid 512 (2 blocks/CU). LDS 48 KB.
// ---------------------------------------------------------------------------
__global__ __launch_bounds__(256, 2) void k_pv(const u16* __restrict__ vt,
                                               const u16* __restrict__ kanq,
                                               const u16* __restrict__ kank,
                                               float* __restrict__ out) {
  __shared__ u16 Vs[3][128 * 64];   // 48 KB: 3 x (128 rows x 64 u16)
  const int bx = blockIdx.x;
  const int qb = bx >> 5;
  const int g = bx & 31;
  const int b = g >> 3, ds = g & 7;
  const int q0 = qb * 128, d0 = ds * 128;
  const int tid = threadIdx.x, w = tid >> 6, l = tid & 63;
  const int lq = l & 31, h = l >> 5;
  const u16* kq = kanq + (size_t)b * SEQ * 16;
  const u16* kk = kank + (size_t)b * SEQ * 16;
  const u16* vtb = vt + ((size_t)b * DIM + d0) * SEQ;

  const short8 bqf =
      *(const short8*)(kq + (size_t)(q0 + w * 32 + lq) * 16 + h * 8);

  // staging: wave w stages chunks c = w*4+i (8 rows each). Lane l covers
  // row 8c+(l>>3), LDS slot l&7; source seg = (l&7) ^ (l>>3) (involution).
  const u16* glp =
      vtb + (size_t)(w * 32 + (l >> 3)) * SEQ + ((l & 7) ^ (l >> 3)) * 8;

  // read lane constants: row = dt*32+lq; wanted seg = bs+h (bs 0,2,4,6);
  // LDS slot = seg ^ (row&7) = seg ^ (lq&7).
  const int sw = lq & 7;
  const int rbase = lq * 64;
  const int s0 = ((0 + h) ^ sw) * 8;
  const int s1 = ((2 + h) ^ sw) * 8;
  const int s2 = ((4 + h) ^ sw) * 8;
  const int s3 = ((6 + h) ^ sw) * 8;

  const floatx16 z16 = {0.f,0.f,0.f,0.f,0.f,0.f,0.f,0.f,
                        0.f,0.f,0.f,0.f,0.f,0.f,0.f,0.f};
  floatx16 accO[4];
#pragma unroll
  for (int dt = 0; dt < 4; ++dt) accO[dt] = z16;
  f32x2 Lp; Lp[0] = 0.f; Lp[1] = 0.f;

  const f32x2 c16 = {0.16666667f, 0.16666667f};
  const f32x2 ch  = {0.5f, 0.5f};
  const f32x2 c1  = {1.0f, 1.0f};

  auto stage = [&](int sb, int mn) {
#pragma unroll
    for (int i = 0; i < 4; ++i)
      gll16(glp + (size_t)(8 * i) * SEQ + mn, &Vs[sb][(w * 4 + i) * 512]);
  };

  // prologue: chunk0 -> buf0; kk(0)
  stage(0, 0);
  short8 kkA = *(const short8*)(kk + (size_t)(0 + lq) * 16 + h * 8);
  short8 kkB = *(const short8*)(kk + (size_t)(32 + lq) * 16 + h * 8);
  __syncthreads();   // chunk0 landed

  short8 pf1A, pf2A, pf1B, pf2B;

  // t = 0 peeled: stage chunk1->buf1; QK(0)+exp(0) -> pf (no PV yet)
  {
    stage(1, 64);
    const short8 kkcA = kkA, kkcB = kkB;
    kkA = *(const short8*)(kk + (size_t)(64 + lq) * 16 + h * 8);
    kkB = *(const short8*)(kk + (size_t)(64 + 32 + lq) * 16 + h * 8);
    floatx16 scA =
        __builtin_amdgcn_mfma_f32_32x32x16_bf16(kkcA, bqf, z16, 0, 0, 0);
    floatx16 scB =
        __builtin_amdgcn_mfma_f32_32x32x16_bf16(kkcB, bqf, z16, 0, 0, 0);
    f32x2 sum; sum[0] = 0.f; sum[1] = 0.f;
    union { unsigned i[4]; short8 v; } u1a, u2a, u1b, u2b;
#pragma unroll
    for (int j = 0; j < 8; ++j) {
      f32x2 xa; xa[0] = scA[2 * j]; xa[1] = scA[2 * j + 1];
      f32x2 xb; xb[0] = scB[2 * j]; xb[1] = scB[2 * j + 1];
      f32x2 ea = __builtin_elementwise_fma(
          xa, __builtin_elementwise_fma(
                  xa, __builtin_elementwise_fma(xa, c16, ch), c1), c1);
      f32x2 eb = __builtin_elementwise_fma(
          xb, __builtin_elementwise_fma(
                  xb, __builtin_elementwise_fma(xb, c16, ch), c1), c1);
      sum += ea; sum += eb;
      const unsigned wa =
          __builtin_amdgcn_perm(fbits(ea[1]), fbits(ea[0]), 0x07060302u);
      const unsigned wb2 =
          __builtin_amdgcn_perm(fbits(eb[1]), fbits(eb[0]), 0x07060302u);
      if (j < 4) { u1a.i[j] = wa; u1b.i[j] = wb2; }
      else       { u2a.i[j - 4] = wa; u2b.i[j - 4] = wb2; }
    }
    Lp += sum;
    pf1A = u1a.v; pf2A = u2a.v; pf1B = u1b.v; pf2B = u2b.v;
  }

  int rb = 0, sb = 2;   // at iter t: read chunk t-1 from rb, stage t+1 to sb
  for (int t = 1; t < SEQ / 64; ++t) {
    __syncthreads();   // chunk t landed; readers of chunk t-2 done
    const int mn = (t + 1 < SEQ / 64) ? (t + 1) * 64 : 0;
    stage(sb, mn);
    const short8 kkcA = kkA, kkcB = kkB;
    kkA = *(const short8*)(kk + (size_t)(mn + lq) * 16 + h * 8);
    kkB = *(const short8*)(kk + (size_t)(mn + 32 + lq) * 16 + h * 8);

    // QK(t)
    floatx16 scA =
        __builtin_amdgcn_mfma_f32_32x32x16_bf16(kkcA, bqf, z16, 0, 0, 0);
    floatx16 scB =
        __builtin_amdgcn_mfma_f32_32x32x16_bf16(kkcB, bqf, z16, 0, 0, 0);

    // PV(t-1) over buf[rb] interleaved with exp(t) -> new pf
    const u16* vb = &Vs[rb][0];
    f32x2 sum; sum[0] = 0.f; sum[1] = 0.f;
    union { unsigned i[4]; short8 v; } u1a, u2a, u1b, u2b;
#pragma unroll
    for (int dt = 0; dt < 4; ++dt) {
      const int r0 = rbase + dt * 2048;
      short8 a1 = *(const short8*)(vb + r0 + s0);
      short8 a2 = *(const short8*)(vb + r0 + s1);
      short8 a3 = *(const short8*)(vb + r0 + s2);
      short8 a4 = *(const short8*)(vb + r0 + s3);
      accO[dt] = __builtin_amdgcn_mfma_f32_32x32x16_bf16(a1, pf1A, accO[dt], 0, 0, 0);
      accO[dt] = __builtin_amdgcn_mfma_f32_32x32x16_bf16(a2, pf2A, accO[dt], 0, 0, 0);
      accO[dt] = __builtin_amdgcn_mfma_f32_32x32x16_bf16(a3, pf1B, accO[dt], 0, 0, 0);
      accO[dt] = __builtin_amdgcn_mfma_f32_32x32x16_bf16(a4, pf2B, accO[dt], 0, 0, 0);
      // exp chunk: j = 2dt, 2dt+1 (VALU, independent of the MFMAs above)
#pragma unroll
      for (int jj = 0; jj < 2; ++jj) {
        const int j = 2 * dt + jj;
        f32x2 xa; xa[0] = scA[2 * j]; xa[1] = scA[2 * j + 1];
        f32x2 xb; xb[0] = scB[2 * j]; xb[1] = scB[2 * j + 1];
        f32x2 ea = __builtin_elementwise_fma(
            xa, __builtin_elementwise_fma(
                    xa, __builtin_elementwise_fma(xa, c16, ch), c1), c1);
        f32x2 eb = __builtin_elementwise_fma(
            xb, __builtin_elementwise_fma(
                    xb, __builtin_elementwise_fma(xb, c16, ch), c1), c1);
        sum += ea; sum += eb;
        const unsigned wa =
            __builtin_amdgcn_perm(fbits(ea[1]), fbits(ea[0]), 0x07060302u);
        const unsigned wb2 =
            __builtin_amdgcn_perm(fbits(eb[1]), fbits(eb[0]), 0x07060302u);
        if (j < 4) { u1a.i[j] = wa; u1b.i[j] = wb2; }
        else       { u2a.i[j - 4] = wa; u2b.i[j - 4] = wb2; }
      }
    }
    Lp += sum;
    pf1A = u1a.v; pf2A = u2a.v; pf1B = u1b.v; pf2B = u2b.v;

    rb = (rb == 2) ? 0 : rb + 1;
    sb = (sb == 2) ? 0 : sb + 1;
  }

  // epilogue: PV(31) from buf[rb] (== chunk 31; staged at t=30, drained at
  // t=31's barrier, not overwritten since)
  {
    const u16* vb = &Vs[rb][0];
#pragma unroll
    for (int dt = 0; dt < 4; ++dt) {
      const int r0 = rbase + dt * 2048;
      short8 a1 = *(const short8*)(vb + r0 + s0);
      short8 a2 = *(const short8*)(vb + r0 + s1);
      short8 a3 = *(const short8*)(vb + r0 + s2);
      short8 a4 = *(const short8*)(vb + r0 + s3);
      accO[dt] = __builtin_amdgcn_mfma_f32_32x32x16_bf16(a1, pf1A, accO[dt], 0, 0, 0);
      accO[dt] = __builtin_amdgcn_mfma_f32_32x32x16_bf16(a2, pf2A, accO[dt], 0, 0, 0);
      accO[dt] = __builtin_amdgcn_mfma_f32_32x32x16_bf16(a3, pf1B, accO[dt], 0, 0, 0);
      accO[dt] = __builtin_amdgcn_mfma_f32_32x32x16_bf16(a4, pf2B, accO[dt], 0, 0, 0);
    }
  }

  float sden = Lp[0] + Lp[1];
  sden += __shfl_xor(sden, 32, 64);
  const float rinv = 1.f / sden;
  float* ob = out + ((size_t)b * SEQ + q0 + w * 32 + lq) * DIM + d0;
#pragma unroll
  for (int dt = 0; dt < 4; ++dt) {
#pragma unroll
    for (int gi = 0; gi < 4; ++gi) {
      float4 o;
      o.x = accO[dt][gi * 4 + 0] * rinv;
      o.y = accO[dt][gi * 4 + 1] * rinv;
      o.z = accO[dt][gi * 4 + 2] * rinv;
      o.w = accO[dt][gi * 4 + 3] * rinv;
      *(float4*)(ob + dt * 32 + gi * 8 + h * 4) = o;
    }
  }
}

// ---------------------------------------------------------------------------
extern "C" void kernel_launch(void* const* d_in, const int* in_sizes, int n_in,
                              void* d_out, int out_size, void* d_ws,
                              size_t ws_size, hipStream_t stream) {
  const float* x = (const float*)d_in[0];
  const float* basis = (const float*)d_in[1];
  const float* Wq = (const float*)d_in[2];
  const float* bq = (const float*)d_in[3];
  const float* Wk = (const float*)d_in[4];
  const float* bk = (const float*)d_in[5];
  const float* Wv = (const float*)d_in[6];
  const float* bv = (const float*)d_in[7];
  float* out = (float*)d_out;
  char* w8 = (char*)d_ws;
  u16* xbf = (u16*)(w8 + OFF_XBF);
  u16* vt = (u16*)(w8 + OFF_VT);
  u16* wb = (u16*)(w8 + OFF_WB);
  u16* kanq = (u16*)(w8 + OFF_KANQ);
  u16* kank = (u16*)(w8 + OFF_KANK);
  float* bkan = (float*)(w8 + OFF_BKAN);

  k_misc<<<2337, 512, 0, stream>>>(x, basis, Wq, bq, Wk, bk, Wv, xbf, wb, bkan);
  k_gemm<<<1152, 256, 0, stream>>>(xbf, wb, bv, bkan, vt, kanq, kank);
  k_pv<<<512, 256, 0, stream>>>(vt, kanq, kank, out);
}